// Round 10
// baseline (49.917 us; speedup 1.0000x reference)
//
#include <hip/hip_runtime.h>

// Window_Crop: sliding-window avgpool over 5 aspect ratios + argmax (grps 0-3).
//
// Ratios: (32,32)off0 (25,39)off6561 (39,25)off13073 (38,26)off19585
//         (26,38)off26110, total 32635. OH=113-KH, OW=113-KW.
//
// R1-R9 model: throughput = independent blocks in flight / block latency.
// This version: each image -> TWO half-image blocks (window rows split at
// h0=ceil(OH/2) per group; a half needs <=75 image rows). LDS = 76x113 fp32
// = 34.4 KB -> 4 blocks/CU, grid=2048 = exactly 2 balanced rounds.
// Halves merged by a tiny combine kernel via d_ws.

#define B_TOTAL 1024
#define HW      112
#define NPIX    (HW * HW)
#define PITCH   113
#define ROWS    75                   // image rows per half-slice
#define SROWS   (ROWS + 1)           // + zero row
#define ISZ     (SROWS * PITCH)      // 8588 floats = 34,352 B
#define TOTAL_W 32635
#define BLOCK   384
#define GRID    2048
#define R0_BOT  37                   // min over groups of h0
#define NVL     ((ROWS * HW) / 4)    // 2100 float4 per slice

// group geometry: KH,KW,OFF,h0 (h0 = ceil(OH/2))
//   g0 32,32 off0     OH81 h0 41
//   g1 25,39 off6561  OH88 h0 44
//   g2 39,25 off13073 OH74 h0 37
//   g3 38,26 off19585 OH75 h0 38
//   g4 26,38 off26110 OH87 h0 44

template<int KH, int KW, int OFF, bool TRACK>
__device__ __forceinline__ void windows_half(const float* __restrict__ S,
                                             float* __restrict__ out_scores,
                                             int tid, int i_lo, int i_hi, int R0,
                                             float& bestv, int& besti) {
    constexpr int OW = HW - KW + 1;
    constexpr int D  = KH * PITCH;
    constexpr float inv = 1.0f / (float)(KH * KW);
    const int nwin = (i_hi - i_lo) * OW;
    const int base_li = i_lo - R0;
    for (int t = tid; t < nwin; t += BLOCK) {
        const int it = t / OW;            // const divisor -> magic mul
        const int j  = t - it * OW;
        const int A  = (base_li + it) * PITCH + j;
        const float s = S[A + D + KW] - S[A + KW] - S[A + D] + S[A];
        const float sc = s * inv;
        const int w = (i_lo + it) * OW + j;
        out_scores[OFF + w] = sc;         // stride-1 lanes: packed stores
        if (TRACK && sc > bestv) { bestv = sc; besti = OFF + w; }
    }
}

__global__ __launch_bounds__(BLOCK, 6)
void window_half_kernel(const float* __restrict__ x, float* __restrict__ out,
                        float2* __restrict__ ws2) {
    __shared__ float S[ISZ];
    __shared__ float wv[BLOCK / 64];
    __shared__ int   wi[BLOCK / 64];

    const int tid  = threadIdx.x;
    const int lane = tid & 63;
    const int bid  = blockIdx.x;
    const int b    = bid >> 1;
    const int h    = bid & 1;
    const int R0   = h ? R0_BOT : 0;

    // zero border row 0 and col 0
    for (int i = tid; i < PITCH; i += BLOCK) {
        S[i] = 0.0f;
        if (i < SROWS) S[i * PITCH] = 0.0f;
    }

    // load 75 rows of the image into S rows 1..75 (float4, coalesced)
    const float4* img4 = (const float4*)(x + (size_t)b * NPIX + R0 * HW);
    for (int i = tid; i < NVL; i += BLOCK) {
        const int r  = i / (HW / 4);
        const int c4 = (i - r * (HW / 4)) * 4;
        const float4 v = img4[i];
        float* dst = &S[(r + 1) * PITCH + c4 + 1];
        dst[0] = v.x; dst[1] = v.y; dst[2] = v.z; dst[3] = v.w;
    }
    __syncthreads();

    // row scan: 75 rows x 4 segments of 28 (300 threads). Partials in regs,
    // shfl fixup (4-lane groups, wave-aligned: 16 rows/wave).
    if (tid < ROWS * 4) {
        const int r = tid >> 2, s = tid & 3;
        const int bl = lane & ~3;
        float* row = &S[(r + 1) * PITCH];
        const int c0 = 1 + s * 28;
        float pref[28];
        float run = 0.0f;
        #pragma unroll
        for (int k = 0; k < 28; ++k) { run += row[c0 + k]; pref[k] = run; }
        const float v0 = __shfl(run, bl, 64), v1 = __shfl(run, bl + 1, 64),
                    v2 = __shfl(run, bl + 2, 64);
        float off = 0.0f;
        if (s > 0) off += v0;
        if (s > 1) off += v1;
        if (s > 2) off += v2;
        #pragma unroll
        for (int k = 0; k < 28; ++k) row[c0 + k] = pref[k] + off;
    }
    __syncthreads();

    // col scan: 112 cols x 2 segments (38 + 37 rows), 224 threads.
    // shfl fixup over lane pairs.
    if (tid < HW * 2) {
        const int c = tid >> 1, s = tid & 1;
        const int bl = lane & ~1;
        float* col = &S[c + 1];
        const int r0 = 1 + s * 38;
        const int cnt = s ? 37 : 38;
        float pref[38];
        float run = 0.0f;
        #pragma unroll
        for (int k = 0; k < 38; ++k) {
            if (k < cnt) { run += col[(r0 + k) * PITCH]; pref[k] = run; }
        }
        const float v0 = __shfl(run, bl, 64);
        const float off = s ? v0 : 0.0f;
        #pragma unroll
        for (int k = 0; k < 38; ++k) {
            if (k < cnt) col[(r0 + k) * PITCH] = pref[k] + off;
        }
    }
    __syncthreads();

    // window scores for this half of every group + argmax over groups 0..3
    float bestv = -3.402823466e+38f;
    int   besti = 0;
    float* out_scores = out + 2 * B_TOTAL + (size_t)b * TOTAL_W;

    if (h == 0) {
        windows_half<32, 32,     0, true >(S, out_scores, tid,  0, 41, R0, bestv, besti);
        windows_half<25, 39,  6561, true >(S, out_scores, tid,  0, 44, R0, bestv, besti);
        windows_half<39, 25, 13073, true >(S, out_scores, tid,  0, 37, R0, bestv, besti);
        windows_half<38, 26, 19585, true >(S, out_scores, tid,  0, 38, R0, bestv, besti);
        windows_half<26, 38, 26110, false>(S, out_scores, tid,  0, 44, R0, bestv, besti);
    } else {
        windows_half<32, 32,     0, true >(S, out_scores, tid, 41, 81, R0, bestv, besti);
        windows_half<25, 39,  6561, true >(S, out_scores, tid, 44, 88, R0, bestv, besti);
        windows_half<39, 25, 13073, true >(S, out_scores, tid, 37, 74, R0, bestv, besti);
        windows_half<38, 26, 19585, true >(S, out_scores, tid, 38, 75, R0, bestv, besti);
        windows_half<26, 38, 26110, false>(S, out_scores, tid, 44, 87, R0, bestv, besti);
    }

    // wave argmax (first-index tie-break), then block combine
    #pragma unroll
    for (int d = 32; d > 0; d >>= 1) {
        const float ov = __shfl_down(bestv, d, 64);
        const int   oi = __shfl_down(besti, d, 64);
        if (ov > bestv || (ov == bestv && oi < besti)) { bestv = ov; besti = oi; }
    }
    if (lane == 0) { wv[tid >> 6] = bestv; wi[tid >> 6] = besti; }
    __syncthreads();
    if (tid == 0) {
        float bv = wv[0]; int bi = wi[0];
        #pragma unroll
        for (int k = 1; k < BLOCK / 64; ++k) {
            if (wv[k] > bv || (wv[k] == bv && wi[k] < bi)) { bv = wv[k]; bi = wi[k]; }
        }
        ws2[bid] = make_float2(bv, (float)bi);
    }
}

__global__ __launch_bounds__(256)
void combine_kernel(const float2* __restrict__ ws2, float* __restrict__ out) {
    const int b = blockIdx.x * 256 + threadIdx.x;
    if (b < B_TOTAL) {
        const float2 a = ws2[2 * b];
        const float2 c = ws2[2 * b + 1];
        float bv = a.x; float bi = a.y;
        if (c.x > bv || (c.x == bv && c.y < bi)) { bv = c.x; bi = c.y; }
        out[b]           = bi;    // idx (exact in fp32: < 2^24)
        out[B_TOTAL + b] = bv;    // prop_scores
    }
}

extern "C" void kernel_launch(void* const* d_in, const int* in_sizes, int n_in,
                              void* d_out, int out_size, void* d_ws, size_t ws_size,
                              hipStream_t stream) {
    const float* x = (const float*)d_in[0];
    float* out     = (float*)d_out;
    float2* ws2    = (float2*)d_ws;
    window_half_kernel<<<GRID, BLOCK, 0, stream>>>(x, out, ws2);
    combine_kernel<<<B_TOTAL / 256, 256, 0, stream>>>(ws2, out);
}